// Round 8
// baseline (344.179 us; speedup 1.0000x reference)
//
#include <hip/hip_runtime.h>
#include <hip/hip_fp16.h>

#define CIN 32
#define COUT 32
#define KK 9
#define PIX 65536          // 256*256 input pixels
#define OH 512
#define OW 512
#define OHOW (OH*OW)
#define NCH 64             // B*COUT
#define TW 16              // tile width  (x)
#define TH 4               // tile height (y)
#define TPX (TW*TH)        // 64 px per tile
#define NTX (OW/TW)        // 32
#define NTY (OH/TH)        // 128
#define NTILE (NTX*NTY)    // 4096
#define NBIN NTILE         // per-tile bins
#define NPK (PIX*KK)       // 589824 (p,k) pairs
#define NSEG 4             // bins segmented by source blockIdx&3 (~XCD pairs)
#define SCAP 96            // per-(bin,seg) capacity; lambda~48, P(ovfl)~1e-4 grid-wide
#define CAPT (NSEG*SCAP)   // 384 entries per tile max
#define NBLK 1024          // fused grid: 4 blocks/CU, guaranteed co-resident

// ---- ws layout (bytes) ----
#define OFF_CNT 0                              // u32[NSEG][NBIN] 64 KB (seg-major)
#define OFF_DONE (128*1024)                    // u32 grid-barrier flag
#define OFF_WT  (256*1024)                     // bf16 hi[9216] + lo[9216] = 36.9 KB
#define OFF_ENT (512*1024)                     // uint2[NBIN*NSEG*SCAP]  12.6 MB
#define OFF_CB  (OFF_ENT + (size_t)NBIN*NSEG*SCAP*8) // f16[NPK*64] 75.5 MB
#define WS_NEED (OFF_CB + (size_t)NPK*NCH*2)   // ~88.6 MB

typedef __bf16    bf16x8 __attribute__((ext_vector_type(8)));
typedef _Float16  f16x8  __attribute__((ext_vector_type(8)));
typedef float     f32x4  __attribute__((ext_vector_type(4)));

__device__ __forceinline__ unsigned short f2h(float v)
{
    return __half_as_ushort(__float2half_rn(v));
}

// corner setup (clips never fire for this input; kept for safety)
__device__ __forceinline__ void corners(float sx, float sy,
    int& x0, int& y0, int& x1, int& y1, float& dx, float& dy)
{
    const float x0f = floorf(sx), y0f = floorf(sy);
    dx = sx - x0f; dy = sy - y0f;
    x0 = min(max((int)x0f, 0), OW - 1);
    y0 = min(max((int)y0f, 0), OH - 1);
    x1 = min(x0 + 1, OW - 1);
    y1 = min(y0 + 1, OH - 1);
}

// ============ pass 0: zero cnt+done, W[i][o][k] -> bf16 hi/lo [k][o][i] ======
__global__ __launch_bounds__(256) void k_init(
    const float* __restrict__ w, __bf16* __restrict__ wth,
    __bf16* __restrict__ wtl, unsigned* __restrict__ cnt,
    unsigned* __restrict__ done)
{
    const int t = blockIdx.x * 256 + threadIdx.x;
    if (t == 0) *done = 0;
    if (t < NSEG * NBIN) cnt[t] = 0;
    if (t < KK * COUT * CIN) {
        const int i = t & 31;
        const int o = (t >> 5) & 31;
        const int k = t >> 10;
        const float v = w[(i * COUT + o) * KK + k];
        const __bf16 h = (__bf16)v;
        wth[t] = h;
        wtl[t] = (__bf16)(v - (float)h);
    }
}

// ---- gather helpers (validated round-7 bodies) ----
#define LOADU(UU, ITb) { \
    _Pragma("unroll") \
    for (int j = 0; j < 16; ++j) { \
        const unsigned idx = (unsigned)((ITb) * 64 + wv * 16 + j); \
        unsigned short v = 0; \
        if (idx < count) \
            v = cb[((size_t)(elist[idx].x & 0xFFFFFu) << 6) + lane]; \
        UU[j] = v; \
    } }

#define BATCH_BODY(ITc, UU) { \
    { uint4* wq = (uint4*)Wb; const uint4 z = make_uint4(0u,0u,0u,0u); \
      wq[tid] = z; wq[tid + 256] = z; } \
    __syncthreads(); \
    { const int eL = tid >> 2, cn = tid & 3; \
      const unsigned idx = (unsigned)((ITc) * 64 + eL); \
      if (idx < count) { \
        const uint2 r = elist[idx]; \
        const int lx = (int)((r.x >> 20) & 31) - 1 + (cn & 1); \
        const int ly = (int)((r.x >> 25) & 7) - 1 + (cn >> 1); \
        if (((unsigned)lx < TW) & ((unsigned)ly < TH)) { \
            const float dx = __half2float(__ushort_as_half((unsigned short)(r.y & 0xFFFF))); \
            const float dy = __half2float(__ushort_as_half((unsigned short)(r.y >> 16))); \
            const float wx = (cn & 1) ? dx : 1.f - dx; \
            const float wy = (cn >> 1) ? dy : 1.f - dy; \
            const int px = ly * TW + lx; \
            Wb[px * 64 + (eL ^ ((px & 7) << 3))] = f2h(wx * wy); \
        } } } \
    { uint4* cvq = (uint4*)Cv; \
      const uint4 pk0 = make_uint4( \
        (unsigned)UU[0]  | ((unsigned)UU[1]  << 16), (unsigned)UU[2]  | ((unsigned)UU[3]  << 16), \
        (unsigned)UU[4]  | ((unsigned)UU[5]  << 16), (unsigned)UU[6]  | ((unsigned)UU[7]  << 16)); \
      const uint4 pk1 = make_uint4( \
        (unsigned)UU[8]  | ((unsigned)UU[9]  << 16), (unsigned)UU[10] | ((unsigned)UU[11] << 16), \
        (unsigned)UU[12] | ((unsigned)UU[13] << 16), (unsigned)UU[14] | ((unsigned)UU[15] << 16)); \
      cvq[lane * 8 + ((wv * 2)     ^ (lane & 7))] = pk0; \
      cvq[lane * 8 + ((wv * 2 + 1) ^ (lane & 7))] = pk1; } \
    __syncthreads(); \
    { const int m = lane & 15, kh = lane >> 4; \
      const int px = wv * 16 + m; \
      const f16x8 af0 = *(const f16x8*)(Wb + px * 64 + ((kh       ^ (px & 7)) << 3)); \
      const f16x8 af1 = *(const f16x8*)(Wb + px * 64 + (((4 + kh) ^ (px & 7)) << 3)); \
      _Pragma("unroll") \
      for (int n = 0; n < 4; ++n) { \
        const int ch = n * 16 + m; \
        const f16x8 bf0 = *(const f16x8*)(Cv + ch * 64 + ((kh       ^ (ch & 7)) << 3)); \
        acc[n] = __builtin_amdgcn_mfma_f32_16x16x32_f16(af0, bf0, acc[n], 0, 0, 0); \
        const f16x8 bf1 = *(const f16x8*)(Cv + ch * 64 + (((4 + kh) ^ (ch & 7)) << 3)); \
        acc[n] = __builtin_amdgcn_mfma_f32_16x16x32_f16(af1, bf1, acc[n], 0, 0, 0); } } \
    __syncthreads(); }

// ============ fused contrib + gather with flag-based grid barrier ============
// 1024 blocks x 256 thr, __launch_bounds__(256,4): LDS 19.7KB x 4 = 79KB < 160,
// VGPR capped 128 -> all 1024 blocks co-resident by construction, so the spin
// barrier cannot deadlock (bounded spin turns a surprise into a visible fail).
// Release: pre-barrier __syncthreads drains each wave's vmem (vmcnt(0)),
// thread0 __threadfence() (wbL2) + device atomicAdd publishes. Acquire: spin
// via AGENT-scope atomic load (bypasses L2), then __threadfence() (invL2) so
// cb/ent/cnt reads are fresh across non-coherent XCD L2s.
__global__ __launch_bounds__(256, 4) void k_fused(
    const float* __restrict__ x, const __bf16* __restrict__ wth,
    const __bf16* __restrict__ wtl, const float* __restrict__ smap,
    unsigned short* __restrict__ cb, unsigned* __restrict__ cnt,
    uint2* __restrict__ ent, const float* __restrict__ bias,
    float* __restrict__ out, unsigned* __restrict__ done)
{
    __shared__ __align__(16) unsigned char sbuf[19712];
    const int tid = threadIdx.x, lane = tid & 63;
    const int wu = __builtin_amdgcn_readfirstlane(tid >> 6);   // uniform wave id
    const int wv = wu;
    const int p0 = blockIdx.x * 64;
    const unsigned seg = blockIdx.x & 3;
    const int colp = lane & 15;          // px within wave / o within 16 / B-col
    const int q    = lane >> 4;          // k-chunk quad
    const int cig  = q * 8;              // ci base for MFMA fragments

    // ================== phase 1: contrib (round-7 body, verbatim) ==========
    {
        unsigned short (*patch)[16][72] =
            (unsigned short (*)[16][72])(sbuf + wu * 4608);    // [2][16][72]/wave

        bf16x8 xh[2], xl[2];
        #pragma unroll
        for (int b = 0; b < 2; ++b) {
            const int p = p0 + wu * 16 + colp;
            #pragma unroll
            for (int j = 0; j < 8; ++j) {
                const float v = x[(size_t)(b * 32 + cig + j) * PIX + p];
                const __bf16 h = (__bf16)v;
                xh[b][j] = h;
                xl[b][j] = (__bf16)(v - (float)h);
            }
        }
        bf16x8 wwh[2][2], wwl[2][2];         // [buf][oh]
        #pragma unroll
        for (int oh = 0; oh < 2; ++oh) {
            wwh[0][oh] = *(const bf16x8*)(wth + (oh * 16 + colp) * 32 + cig);
            wwl[0][oh] = *(const bf16x8*)(wtl + (oh * 16 + colp) * 32 + cig);
        }

        unsigned aS[3][4], aA[3][4], aR[3][4], aW[3];
        #pragma unroll
        for (int it = 0; it < 3; ++it) {
            const int idx = tid + it * 256;
            const bool vit = idx < 576;
            const int t = min(p0 * KK + idx, NPK - 1);
            const float sx = smap[2 * t], sy = smap[2 * t + 1];
            int x0, y0, x1, y1; float dx, dy;
            corners(sx, sy, x0, y0, x1, y1, dx, dy);
            const int g0 = x0 >> 4, g1 = x1 >> 4;   // tile col
            const int t0 = y0 >> 2, t1 = y1 >> 2;   // tile row
            aW[it] = (unsigned)f2h(dx) | ((unsigned)f2h(dy) << 16);
            const bool dg = (g1 != g0), dt = (t1 != t0);
            const bool cond[4] = { vit, vit && dg, vit && dt, vit && dg && dt };
            const int  tys[4]  = { t0, t0, t1, t1 };
            const int  gss[4]  = { g0, g1, g0, g1 };
            #pragma unroll
            for (int e = 0; e < 4; ++e) {
                unsigned slot = 0xFFFFFFFFu;
                const int bin = tys[e] * 32 + gss[e];
                const unsigned lxb = (unsigned)(x0 - gss[e] * TW + 1);
                const unsigned lyb = (unsigned)(y0 - tys[e] * TH + 1);
                if (cond[e]) slot = atomicAdd(&cnt[seg * NBIN + bin], 1u);
                aS[it][e] = slot;
                aA[it][e] = ((unsigned)bin * NSEG + seg) * SCAP;
                aR[it][e] = (unsigned)t | (lxb << 20) | (lyb << 25);
            }
        }

        const int pxr = lane >> 2, cc = lane & 3;   // flush mapping
        #pragma unroll
        for (int k = 0; k < KK; ++k) {
            const int kb = k & 1;
            const int cur = k & 1, nxt = cur ^ 1;
            if (k + 1 < KK) {                       // prefetch W(k+1)
                const __bf16* wb = wth + (k + 1) * (COUT * CIN);
                const __bf16* lb = wtl + (k + 1) * (COUT * CIN);
                #pragma unroll
                for (int oh = 0; oh < 2; ++oh) {
                    wwh[nxt][oh] = *(const bf16x8*)(wb + (oh * 16 + colp) * 32 + cig);
                    wwl[nxt][oh] = *(const bf16x8*)(lb + (oh * 16 + colp) * 32 + cig);
                }
            }
            #pragma unroll
            for (int cg_ = 0; cg_ < 4; ++cg_) {     // ch group: b=cg>>1, oh=cg&1
                const int b = cg_ >> 1, oh = cg_ & 1;
                f32x4 a = {0.f, 0.f, 0.f, 0.f};
                a = __builtin_amdgcn_mfma_f32_16x16x32_bf16(wwh[cur][oh], xh[b], a, 0, 0, 0);
                a = __builtin_amdgcn_mfma_f32_16x16x32_bf16(wwl[cur][oh], xh[b], a, 0, 0, 0);
                a = __builtin_amdgcn_mfma_f32_16x16x32_bf16(wwh[cur][oh], xl[b], a, 0, 0, 0);
                const unsigned d0 = (unsigned)f2h(a[0]) | ((unsigned)f2h(a[1]) << 16);
                const unsigned d1 = (unsigned)f2h(a[2]) | ((unsigned)f2h(a[3]) << 16);
                *(uint2*)&patch[kb][colp][cg_ * 16 + q * 4] = make_uint2(d0, d1);
            }
            const uint4 a0 = *(const uint4*)&patch[kb][pxr][cc * 8];
            const uint4 a1 = *(const uint4*)&patch[kb][pxr][32 + cc * 8];
            unsigned short* dst = cb + (size_t)(p0 + wu * 16 + pxr) * 576 + k * 64 + cc * 8;
            *(uint4*)dst        = a0;               // 4 lanes = 64B contiguous sector
            *(uint4*)(dst + 32) = a1;
        }

        #pragma unroll
        for (int it = 0; it < 3; ++it) {
            #pragma unroll
            for (int e = 0; e < 4; ++e) {
                if (aS[it][e] < SCAP)
                    ent[(size_t)aA[it][e] + aS[it][e]] = make_uint2(aR[it][e], aW[it]);
            }
        }
    }

    // ================== flag-based grid barrier ==================
    __syncthreads();                 // all waves' stores drained to L2 (vmcnt 0)
    if (tid == 0) {
        __threadfence();             // release: write-back L2
        atomicAdd(done, 1u);         // device-scope
        unsigned v = 0;
        for (long tries = 0; tries < (1L << 22); ++tries) {
            v = __hip_atomic_load(done, __ATOMIC_RELAXED, __HIP_MEMORY_SCOPE_AGENT);
            if (v >= NBLK) break;
            __builtin_amdgcn_s_sleep(8);
        }
        __threadfence();             // acquire: invalidate L2
    }
    __syncthreads();

    // ================== phase 2: gather (round-7 body), 4 tiles =============
    unsigned short* Wb = (unsigned short*)sbuf;          // f16 [64px][64e], swz px&7
    unsigned short* Cv = (unsigned short*)(sbuf + 8192); // f16 [64ch][64e], swz ch&7
    uint2* elist = (uint2*)(sbuf + 16640);               // 3 KB merged entry list

    for (int jt = 0; jt < 4; ++jt) {
        const int bt = (blockIdx.x << 2) | jt;
        const int tx0 = (bt & 31) * TW;
        const int ty0 = (bt >> 5) * TH;

        __syncthreads();             // safety: previous tile fully done with LDS

        const unsigned c0 = min(cnt[0 * NBIN + bt], (unsigned)SCAP);
        const unsigned c1 = min(cnt[1 * NBIN + bt], (unsigned)SCAP);
        const unsigned c2 = min(cnt[2 * NBIN + bt], (unsigned)SCAP);
        const unsigned c3 = min(cnt[3 * NBIN + bt], (unsigned)SCAP);
        const unsigned o1 = c0, o2 = c0 + c1, o3 = o2 + c2;
        const unsigned count = o3 + c3;
        {
            const uint2* e0 = ent + ((size_t)bt * NSEG + 0) * SCAP;
            const uint2* e1 = ent + ((size_t)bt * NSEG + 1) * SCAP;
            const uint2* e2 = ent + ((size_t)bt * NSEG + 2) * SCAP;
            const uint2* e3 = ent + ((size_t)bt * NSEG + 3) * SCAP;
            if ((unsigned)tid < c0) elist[tid]      = e0[tid];
            if ((unsigned)tid < c1) elist[o1 + tid] = e1[tid];
            if ((unsigned)tid < c2) elist[o2 + tid] = e2[tid];
            if ((unsigned)tid < c3) elist[o3 + tid] = e3[tid];
        }
        __syncthreads();

        const int nb = (int)(count + 63) >> 6;

        unsigned short uA[16], uB[16], uC[16], uD[16];
        LOADU(uA, 0); LOADU(uB, 1); LOADU(uC, 2); LOADU(uD, 3);

        f32x4 acc[4] = {{0.f,0.f,0.f,0.f},{0.f,0.f,0.f,0.f},
                        {0.f,0.f,0.f,0.f},{0.f,0.f,0.f,0.f}};

        if (0 < nb) { BATCH_BODY(0, uA); }
        if (1 < nb) { BATCH_BODY(1, uB); }
        if (2 < nb) { BATCH_BODY(2, uC); }
        if (3 < nb) { BATCH_BODY(3, uD); }
        for (int it = 4; it < nb; ++it) {            // rare tail (count > 256)
            unsigned short ut[16];
            LOADU(ut, it);
            BATCH_BODY(it, ut);
        }

        // epilogue: transpose through LDS, coalesced store
        float* stage = (float*)sbuf;                 // overlays W/CV
        #pragma unroll
        for (int n = 0; n < 4; ++n) {
            #pragma unroll
            for (int r = 0; r < 4; ++r)
                stage[(wv * 16 + (lane >> 4) * 4 + r) * 65 + n * 16 + (lane & 15)] = acc[n][r];
        }
        __syncthreads();
        const int py = lane >> 4, pxx = lane & 15;
        const size_t qq = (size_t)(ty0 + py) * OW + tx0 + pxx;
        #pragma unroll
        for (int j = 0; j < 16; ++j) {
            const int c = wv * 16 + j;
            out[(size_t)c * OHOW + qq] = stage[(py * 16 + pxx) * 65 + c] + bias[c & 31];
        }
    }
}

// ================= fallback (no ws requirement) ==============================
__global__ __launch_bounds__(576) void mtc_scatter_direct(
    const float* __restrict__ x, const float* __restrict__ weight,
    const float* __restrict__ smap, float* __restrict__ acc)
{
    __shared__ float xs[64][68];
    __shared__ float sm[64 * KK * 2];
    const int t = threadIdx.x;
    const int p0 = blockIdx.x * 64;
    if (t < 512) {
        const int pp = t & 63, c0 = t >> 6;
        #pragma unroll
        for (int ch = 0; ch < 8; ++ch) {
            const int c = c0 + ch * 8;
            xs[pp][c] = x[(size_t)c * PIX + p0 + pp];
        }
    }
    for (int i = t; i < 64 * KK * 2; i += 576)
        sm[i] = smap[(size_t)p0 * (KK * 2) + i];
    const int k = t >> 6, lane = t & 63, b = lane >> 5, o = lane & 31;
    float wreg[CIN];
    #pragma unroll
    for (int i = 0; i < CIN; ++i) wreg[i] = weight[(i * COUT + o) * KK + k];
    __syncthreads();
    for (int pp = 0; pp < 64; ++pp) {
        const float sx = sm[(pp * KK + k) * 2], sy = sm[(pp * KK + k) * 2 + 1];
        int x0, y0, x1, y1; float dx, dy;
        corners(sx, sy, x0, y0, x1, y1, dx, dy);
        const float* xrow = &xs[pp][b * 32];
        float cv = 0.f;
        #pragma unroll
        for (int j = 0; j < 8; ++j) {
            const float4 xv = *(const float4*)(xrow + 4 * j);
            cv += xv.x * wreg[4*j] + xv.y * wreg[4*j+1] + xv.z * wreg[4*j+2] + xv.w * wreg[4*j+3];
        }
        const size_t base = (size_t)lane * OHOW;
        atomicAdd(&acc[base + y0 * OW + x0], cv * (1.f - dx) * (1.f - dy));
        atomicAdd(&acc[base + y0 * OW + x1], cv * dx * (1.f - dy));
        atomicAdd(&acc[base + y1 * OW + x0], cv * (1.f - dx) * dy);
        atomicAdd(&acc[base + y1 * OW + x1], cv * dx * dy);
    }
}

__global__ __launch_bounds__(256) void mtc_bias_add(
    float* __restrict__ out, const float* __restrict__ bias)
{
    const size_t i = (size_t)blockIdx.x * 256 + threadIdx.x;
    out[i] += bias[(i >> 18) & 31];
}

extern "C" void kernel_launch(void* const* d_in, const int* in_sizes, int n_in,
                              void* d_out, int out_size, void* d_ws, size_t ws_size,
                              hipStream_t stream) {
    const float* x      = (const float*)d_in[0];
    const float* weight = (const float*)d_in[1];
    const float* bias   = (const float*)d_in[2];
    const float* smap   = (const float*)d_in[3];
    float* out = (float*)d_out;
    char* ws = (char*)d_ws;

    if (ws_size >= WS_NEED) {
        unsigned* cnt  = (unsigned*)(ws + OFF_CNT);
        unsigned* done = (unsigned*)(ws + OFF_DONE);
        __bf16* wth    = (__bf16*)(ws + OFF_WT);
        __bf16* wtl    = wth + KK * COUT * CIN;
        uint2* ent     = (uint2*)(ws + OFF_ENT);
        unsigned short* cb = (unsigned short*)(ws + OFF_CB);

        k_init<<<64, 256, 0, stream>>>(weight, wth, wtl, cnt, done);
        k_fused<<<NBLK, 256, 0, stream>>>(x, wth, wtl, smap, cb, cnt, ent,
                                          bias, out, done);
    } else {
        hipMemsetAsync(out, 0, (size_t)OHOW * NCH * sizeof(float), stream);
        mtc_scatter_direct<<<PIX / 64, 576, 0, stream>>>(x, weight, smap, out);
        mtc_bias_add<<<(OHOW * NCH) / 256, 256, 0, stream>>>(out, bias);
    }
}

// Round 10
// 166.462 us; speedup vs baseline: 2.0676x; 2.0676x over previous
//
#include <hip/hip_runtime.h>
#include <hip/hip_fp16.h>

#define CIN 32
#define COUT 32
#define KK 9
#define PIX 65536          // 256*256 input pixels
#define OH 512
#define OW 512
#define OHOW (OH*OW)
#define NCH 64             // B*COUT
#define TW 16              // tile width  (x)
#define TH 4               // tile height (y)
#define TPX (TW*TH)        // 64 px per tile
#define NTX (OW/TW)        // 32
#define NTY (OH/TH)        // 128
#define NTILE (NTX*NTY)    // 4096
#define NBIN NTILE         // per-tile bins
#define NPK (PIX*KK)       // 589824 (p,k) pairs
#define NSEG 4             // bins segmented by source blockIdx&3 (~XCD pairs)
#define SCAP 96            // per-(bin,seg) capacity; lambda~48, P(ovfl)~1e-4 grid-wide
#define CAPT (NSEG*SCAP)   // 384 entries per tile max

// ---- ws layout (bytes) ----
#define OFF_CNT 0                              // u32[NSEG][NBIN] 64 KB (seg-major)
#define OFF_WT  (256*1024)                     // bf16 hi[9216] + lo[9216] = 36.9 KB
#define OFF_ENT (512*1024)                     // uint2[NBIN*NSEG*SCAP]  12.6 MB
#define OFF_CB  (OFF_ENT + (size_t)NBIN*NSEG*SCAP*8) // f16[NPK*64] 75.5 MB
#define WS_NEED (OFF_CB + (size_t)NPK*NCH*2)   // ~88.6 MB

typedef __bf16    bf16x8 __attribute__((ext_vector_type(8)));
typedef _Float16  f16x8  __attribute__((ext_vector_type(8)));
typedef float     f32x4  __attribute__((ext_vector_type(4)));

__device__ __forceinline__ unsigned short f2h(float v)
{
    return __half_as_ushort(__float2half_rn(v));
}

// corner setup (clips never fire for this input; kept for safety)
__device__ __forceinline__ void corners(float sx, float sy,
    int& x0, int& y0, int& x1, int& y1, float& dx, float& dy)
{
    const float x0f = floorf(sx), y0f = floorf(sy);
    dx = sx - x0f; dy = sy - y0f;
    x0 = min(max((int)x0f, 0), OW - 1);
    y0 = min(max((int)y0f, 0), OH - 1);
    x1 = min(x0 + 1, OW - 1);
    y1 = min(y0 + 1, OH - 1);
}

// ============ pass 0: zero cnt + W[i][o][k] -> bf16 hi/lo [k][o][i] ==========
__global__ __launch_bounds__(256) void k_init(
    const float* __restrict__ w, __bf16* __restrict__ wth,
    __bf16* __restrict__ wtl, unsigned* __restrict__ cnt)
{
    const int t = blockIdx.x * 256 + threadIdx.x;
    if (t < NSEG * NBIN) cnt[t] = 0;
    if (t < KK * COUT * CIN) {
        const int i = t & 31;
        const int o = (t >> 5) & 31;
        const int k = t >> 10;
        const float v = w[(i * COUT + o) * KK + k];
        const __bf16 h = (__bf16)v;
        wth[t] = h;
        wtl[t] = (__bf16)(v - (float)h);
    }
}

// ============ pass 1: contrib via MFMA; binning atomics moved to the TAIL ====
// vmcnt decrements IN ISSUE ORDER: any atomic issued before the k-loop forces
// every k-loop W-prefetch wait to cover the atomic's fabric round trip. So
// phase A is now compute-only (bin/record in registers, sentinel = invalid);
// the k-loop runs with a clean vmem queue; all 12 independent atomics fire
// after the k-loop, then a separate store loop consumes the returns (first
// store waits ~one pipelined atomic latency; the rest are already back).
__global__ __launch_bounds__(256, 1) void k_contrib7(
    const float* __restrict__ x, const __bf16* __restrict__ wth,
    const __bf16* __restrict__ wtl, const float* __restrict__ smap,
    unsigned short* __restrict__ cb, unsigned* __restrict__ cnt,
    uint2* __restrict__ ent)
{
    __shared__ __align__(16) unsigned short patch[4][2][16][72]; // 18.4 KB
    const int tid = threadIdx.x, lane = tid & 63;
    const int wu = __builtin_amdgcn_readfirstlane(tid >> 6);   // uniform wave id
    const int p0 = blockIdx.x * 64;
    const unsigned seg = blockIdx.x & 3;
    const int colp = lane & 15;          // px within wave / o within 16 / B-col
    const int q    = lane >> 4;          // k-chunk quad
    const int cig  = q * 8;              // ci base for MFMA fragments

    // ---- x fragments first ----
    bf16x8 xh[2], xl[2];
    #pragma unroll
    for (int b = 0; b < 2; ++b) {
        const int p = p0 + wu * 16 + colp;
        #pragma unroll
        for (int j = 0; j < 8; ++j) {
            const float v = x[(size_t)(b * 32 + cig + j) * PIX + p];
            const __bf16 h = (__bf16)v;
            xh[b][j] = h;
            xl[b][j] = (__bf16)(v - (float)h);
        }
    }
    bf16x8 wwh[2][2], wwl[2][2];         // [buf][oh]
    #pragma unroll
    for (int oh = 0; oh < 2; ++oh) {
        wwh[0][oh] = *(const bf16x8*)(wth + (oh * 16 + colp) * 32 + cig);
        wwl[0][oh] = *(const bf16x8*)(wtl + (oh * 16 + colp) * 32 + cig);
    }

    // ---- phase A: COMPUTE-ONLY binning (no atomics, no stores) ----
    unsigned aBin[3][4], aR[3][4], aW[3];
    #pragma unroll
    for (int it = 0; it < 3; ++it) {
        const int idx = tid + it * 256;
        const bool vit = idx < 576;
        const int t = min(p0 * KK + idx, NPK - 1);
        const float sx = smap[2 * t], sy = smap[2 * t + 1];
        int x0, y0, x1, y1; float dx, dy;
        corners(sx, sy, x0, y0, x1, y1, dx, dy);
        const int g0 = x0 >> 4, g1 = x1 >> 4;   // tile col
        const int t0 = y0 >> 2, t1 = y1 >> 2;   // tile row
        aW[it] = (unsigned)f2h(dx) | ((unsigned)f2h(dy) << 16);
        const bool dg = (g1 != g0), dt = (t1 != t0);
        const bool cond[4] = { vit, vit && dg, vit && dt, vit && dg && dt };
        const int  tys[4]  = { t0, t0, t1, t1 };
        const int  gss[4]  = { g0, g1, g0, g1 };
        #pragma unroll
        for (int e = 0; e < 4; ++e) {
            const unsigned lxb = (unsigned)(x0 - gss[e] * TW + 1);
            const unsigned lyb = (unsigned)(y0 - tys[e] * TH + 1);
            aBin[it][e] = cond[e] ? (unsigned)(tys[e] * 32 + gss[e]) : 0xFFFFFFFFu;
            aR[it][e] = (unsigned)t | (lxb << 20) | (lyb << 25);
        }
    }

    // ---- k-loop: MFMA -> per-wave LDS patch -> full-sector stores ----
    const int pxr = lane >> 2, cc = lane & 3;   // flush mapping
    #pragma unroll
    for (int k = 0; k < KK; ++k) {
        const int kb = k & 1;
        const int cur = k & 1, nxt = cur ^ 1;
        if (k + 1 < KK) {                       // prefetch W(k+1)
            const __bf16* wb = wth + (k + 1) * (COUT * CIN);
            const __bf16* lb = wtl + (k + 1) * (COUT * CIN);
            #pragma unroll
            for (int oh = 0; oh < 2; ++oh) {
                wwh[nxt][oh] = *(const bf16x8*)(wb + (oh * 16 + colp) * 32 + cig);
                wwl[nxt][oh] = *(const bf16x8*)(lb + (oh * 16 + colp) * 32 + cig);
            }
        }
        #pragma unroll
        for (int cg_ = 0; cg_ < 4; ++cg_) {     // ch group: b=cg>>1, oh=cg&1
            const int b = cg_ >> 1, oh = cg_ & 1;
            f32x4 a = {0.f, 0.f, 0.f, 0.f};
            a = __builtin_amdgcn_mfma_f32_16x16x32_bf16(wwh[cur][oh], xh[b], a, 0, 0, 0);
            a = __builtin_amdgcn_mfma_f32_16x16x32_bf16(wwl[cur][oh], xh[b], a, 0, 0, 0);
            a = __builtin_amdgcn_mfma_f32_16x16x32_bf16(wwh[cur][oh], xl[b], a, 0, 0, 0);
            const unsigned d0 = (unsigned)f2h(a[0]) | ((unsigned)f2h(a[1]) << 16);
            const unsigned d1 = (unsigned)f2h(a[2]) | ((unsigned)f2h(a[3]) << 16);
            *(uint2*)&patch[wu][kb][colp][cg_ * 16 + q * 4] = make_uint2(d0, d1);
        }
        const uint4 a0 = *(const uint4*)&patch[wu][kb][pxr][cc * 8];
        const uint4 a1 = *(const uint4*)&patch[wu][kb][pxr][32 + cc * 8];
        unsigned short* dst = cb + (size_t)(p0 + wu * 16 + pxr) * 576 + k * 64 + cc * 8;
        *(uint4*)dst        = a0;               // 4 lanes = 64B contiguous sector
        *(uint4*)(dst + 32) = a1;
    }

    // ---- phase D: fire ALL atomics (independent), then dependent stores ----
    unsigned aS[3][4];
    #pragma unroll
    for (int it = 0; it < 3; ++it) {
        #pragma unroll
        for (int e = 0; e < 4; ++e) {
            unsigned raw = 0xFFFFFFFFu;
            if (aBin[it][e] != 0xFFFFFFFFu)
                raw = atomicAdd(&cnt[seg * NBIN + aBin[it][e]], 1u);
            aS[it][e] = raw;
        }
    }
    #pragma unroll
    for (int it = 0; it < 3; ++it) {
        #pragma unroll
        for (int e = 0; e < 4; ++e) {
            if (aS[it][e] < SCAP)
                ent[(size_t)(aBin[it][e] * NSEG + seg) * SCAP + aS[it][e]] =
                    make_uint2(aR[it][e], aW[it]);
        }
    }
}

// ---- gather helpers (round-7 verbatim) ----
#define LOADU(UU, ITb) { \
    _Pragma("unroll") \
    for (int j = 0; j < 16; ++j) { \
        const unsigned idx = (unsigned)((ITb) * 64 + wv * 16 + j); \
        unsigned short v = 0; \
        if (idx < count) \
            v = cb[((size_t)(elist[idx].x & 0xFFFFFu) << 6) + lane]; \
        UU[j] = v; \
    } }

#define BATCH_BODY(ITc, UU) { \
    { uint4* wq = (uint4*)Wb; const uint4 z = make_uint4(0u,0u,0u,0u); \
      wq[tid] = z; wq[tid + 256] = z; } \
    __syncthreads(); \
    { const int eL = tid >> 2, cn = tid & 3; \
      const unsigned idx = (unsigned)((ITc) * 64 + eL); \
      if (idx < count) { \
        const uint2 r = elist[idx]; \
        const int lx = (int)((r.x >> 20) & 31) - 1 + (cn & 1); \
        const int ly = (int)((r.x >> 25) & 7) - 1 + (cn >> 1); \
        if (((unsigned)lx < TW) & ((unsigned)ly < TH)) { \
            const float dx = __half2float(__ushort_as_half((unsigned short)(r.y & 0xFFFF))); \
            const float dy = __half2float(__ushort_as_half((unsigned short)(r.y >> 16))); \
            const float wx = (cn & 1) ? dx : 1.f - dx; \
            const float wy = (cn >> 1) ? dy : 1.f - dy; \
            const int px = ly * TW + lx; \
            Wb[px * 64 + (eL ^ ((px & 7) << 3))] = f2h(wx * wy); \
        } } } \
    { uint4* cvq = (uint4*)Cv; \
      const uint4 pk0 = make_uint4( \
        (unsigned)UU[0]  | ((unsigned)UU[1]  << 16), (unsigned)UU[2]  | ((unsigned)UU[3]  << 16), \
        (unsigned)UU[4]  | ((unsigned)UU[5]  << 16), (unsigned)UU[6]  | ((unsigned)UU[7]  << 16)); \
      const uint4 pk1 = make_uint4( \
        (unsigned)UU[8]  | ((unsigned)UU[9]  << 16), (unsigned)UU[10] | ((unsigned)UU[11] << 16), \
        (unsigned)UU[12] | ((unsigned)UU[13] << 16), (unsigned)UU[14] | ((unsigned)UU[15] << 16)); \
      cvq[lane * 8 + ((wv * 2)     ^ (lane & 7))] = pk0; \
      cvq[lane * 8 + ((wv * 2 + 1) ^ (lane & 7))] = pk1; } \
    __syncthreads(); \
    { const int m = lane & 15, kh = lane >> 4; \
      const int px = wv * 16 + m; \
      const f16x8 af0 = *(const f16x8*)(Wb + px * 64 + ((kh       ^ (px & 7)) << 3)); \
      const f16x8 af1 = *(const f16x8*)(Wb + px * 64 + (((4 + kh) ^ (px & 7)) << 3)); \
      _Pragma("unroll") \
      for (int n = 0; n < 4; ++n) { \
        const int ch = n * 16 + m; \
        const f16x8 bf0 = *(const f16x8*)(Cv + ch * 64 + ((kh       ^ (ch & 7)) << 3)); \
        acc[n] = __builtin_amdgcn_mfma_f32_16x16x32_f16(af0, bf0, acc[n], 0, 0, 0); \
        const f16x8 bf1 = *(const f16x8*)(Cv + ch * 64 + (((4 + kh) ^ (ch & 7)) << 3)); \
        acc[n] = __builtin_amdgcn_mfma_f32_16x16x32_f16(af1, bf1, acc[n], 0, 0, 0); } } \
    __syncthreads(); }

// ============ pass 2: batched-MFMA gather (round-7 verbatim) =================
__global__ __launch_bounds__(256) void k_gather(
    const unsigned short* __restrict__ cb, const uint2* __restrict__ ent,
    const unsigned* __restrict__ cnt, const float* __restrict__ bias,
    float* __restrict__ out)
{
    __shared__ __align__(16) unsigned char smem[16640]; // W+CV / f32 stage[64][65]
    __shared__ __align__(16) uint2 elist[CAPT];         // 3 KB merged entry list
    unsigned short* Wb = (unsigned short*)smem;          // f16 [64px][64e], swz by px&7
    unsigned short* Cv = (unsigned short*)(smem + 8192); // f16 [64ch][64e], swz by ch&7
    const int tid = threadIdx.x, lane = tid & 63;
    const int wv = __builtin_amdgcn_readfirstlane(tid >> 6);   // wave id 0..3
    const int bt = blockIdx.x;
    const int tx0 = (bt & 31) * TW;
    const int ty0 = (bt >> 5) * TH;

    // ---- merge segment lists into LDS ----
    const unsigned c0 = min(cnt[0 * NBIN + bt], (unsigned)SCAP);
    const unsigned c1 = min(cnt[1 * NBIN + bt], (unsigned)SCAP);
    const unsigned c2 = min(cnt[2 * NBIN + bt], (unsigned)SCAP);
    const unsigned c3 = min(cnt[3 * NBIN + bt], (unsigned)SCAP);
    const unsigned o1 = c0, o2 = c0 + c1, o3 = o2 + c2;
    const unsigned count = o3 + c3;
    {
        const uint2* e0 = ent + ((size_t)bt * NSEG + 0) * SCAP;
        const uint2* e1 = ent + ((size_t)bt * NSEG + 1) * SCAP;
        const uint2* e2 = ent + ((size_t)bt * NSEG + 2) * SCAP;
        const uint2* e3 = ent + ((size_t)bt * NSEG + 3) * SCAP;
        if ((unsigned)tid < c0) elist[tid]      = e0[tid];
        if ((unsigned)tid < c1) elist[o1 + tid] = e1[tid];
        if ((unsigned)tid < c2) elist[o2 + tid] = e2[tid];
        if ((unsigned)tid < c3) elist[o3 + tid] = e3[tid];
    }
    __syncthreads();

    const int nb = (int)(count + 63) >> 6;

    // ---- prefetch ALL (<=4) batches' CV rows into named register arrays ----
    unsigned short uA[16], uB[16], uC[16], uD[16];
    LOADU(uA, 0); LOADU(uB, 1); LOADU(uC, 2); LOADU(uD, 3);

    f32x4 acc[4] = {{0.f,0.f,0.f,0.f},{0.f,0.f,0.f,0.f},
                    {0.f,0.f,0.f,0.f},{0.f,0.f,0.f,0.f}};

    if (0 < nb) { BATCH_BODY(0, uA); }
    if (1 < nb) { BATCH_BODY(1, uB); }
    if (2 < nb) { BATCH_BODY(2, uC); }
    if (3 < nb) { BATCH_BODY(3, uD); }
    // rare tail (count > 256): inline loads
    for (int it = 4; it < nb; ++it) {
        unsigned short ut[16];
        LOADU(ut, it);
        BATCH_BODY(it, ut);
    }

    // ---- epilogue: transpose through LDS, coalesced store ----
    float* stage = (float*)smem;             // 16640 B, overlays W/CV
    #pragma unroll
    for (int n = 0; n < 4; ++n) {
        #pragma unroll
        for (int r = 0; r < 4; ++r)
            stage[(wv * 16 + (lane >> 4) * 4 + r) * 65 + n * 16 + (lane & 15)] = acc[n][r];
    }
    __syncthreads();
    const int py = lane >> 4, pxx = lane & 15;
    const size_t qq = (size_t)(ty0 + py) * OW + tx0 + pxx;
    #pragma unroll
    for (int j = 0; j < 16; ++j) {
        const int c = wv * 16 + j;
        out[(size_t)c * OHOW + qq] = stage[(py * 16 + pxx) * 65 + c] + bias[c & 31];
    }
}

// ================= fallback (no ws requirement) ==============================
__global__ __launch_bounds__(576) void mtc_scatter_direct(
    const float* __restrict__ x, const float* __restrict__ weight,
    const float* __restrict__ smap, float* __restrict__ acc)
{
    __shared__ float xs[64][68];
    __shared__ float sm[64 * KK * 2];
    const int t = threadIdx.x;
    const int p0 = blockIdx.x * 64;
    if (t < 512) {
        const int pp = t & 63, c0 = t >> 6;
        #pragma unroll
        for (int ch = 0; ch < 8; ++ch) {
            const int c = c0 + ch * 8;
            xs[pp][c] = x[(size_t)c * PIX + p0 + pp];
        }
    }
    for (int i = t; i < 64 * KK * 2; i += 576)
        sm[i] = smap[(size_t)p0 * (KK * 2) + i];
    const int k = t >> 6, lane = t & 63, b = lane >> 5, o = lane & 31;
    float wreg[CIN];
    #pragma unroll
    for (int i = 0; i < CIN; ++i) wreg[i] = weight[(i * COUT + o) * KK + k];
    __syncthreads();
    for (int pp = 0; pp < 64; ++pp) {
        const float sx = sm[(pp * KK + k) * 2], sy = sm[(pp * KK + k) * 2 + 1];
        int x0, y0, x1, y1; float dx, dy;
        corners(sx, sy, x0, y0, x1, y1, dx, dy);
        const float* xrow = &xs[pp][b * 32];
        float cv = 0.f;
        #pragma unroll
        for (int j = 0; j < 8; ++j) {
            const float4 xv = *(const float4*)(xrow + 4 * j);
            cv += xv.x * wreg[4*j] + xv.y * wreg[4*j+1] + xv.z * wreg[4*j+2] + xv.w * wreg[4*j+3];
        }
        const size_t base = (size_t)lane * OHOW;
        atomicAdd(&acc[base + y0 * OW + x0], cv * (1.f - dx) * (1.f - dy));
        atomicAdd(&acc[base + y0 * OW + x1], cv * dx * (1.f - dy));
        atomicAdd(&acc[base + y1 * OW + x0], cv * (1.f - dx) * dy);
        atomicAdd(&acc[base + y1 * OW + x1], cv * dx * dy);
    }
}

__global__ __launch_bounds__(256) void mtc_bias_add(
    float* __restrict__ out, const float* __restrict__ bias)
{
    const size_t i = (size_t)blockIdx.x * 256 + threadIdx.x;
    out[i] += bias[(i >> 18) & 31];
}

extern "C" void kernel_launch(void* const* d_in, const int* in_sizes, int n_in,
                              void* d_out, int out_size, void* d_ws, size_t ws_size,
                              hipStream_t stream) {
    const float* x      = (const float*)d_in[0];
    const float* weight = (const float*)d_in[1];
    const float* bias   = (const float*)d_in[2];
    const float* smap   = (const float*)d_in[3];
    float* out = (float*)d_out;
    char* ws = (char*)d_ws;

    if (ws_size >= WS_NEED) {
        unsigned* cnt = (unsigned*)(ws + OFF_CNT);
        __bf16* wth   = (__bf16*)(ws + OFF_WT);
        __bf16* wtl   = wth + KK * COUT * CIN;
        uint2* ent    = (uint2*)(ws + OFF_ENT);
        unsigned short* cb = (unsigned short*)(ws + OFF_CB);

        k_init<<<64, 256, 0, stream>>>(weight, wth, wtl, cnt);
        k_contrib7<<<PIX / 64, 256, 0, stream>>>(x, wth, wtl, smap, cb, cnt, ent);
        k_gather<<<NTILE, 256, 0, stream>>>(cb, ent, cnt, bias, out);
    } else {
        hipMemsetAsync(out, 0, (size_t)OHOW * NCH * sizeof(float), stream);
        mtc_scatter_direct<<<PIX / 64, 576, 0, stream>>>(x, weight, smap, out);
        mtc_bias_add<<<(OHOW * NCH) / 256, 256, 0, stream>>>(out, bias);
    }
}